// Round 2
// baseline (172.342 us; speedup 1.0000x reference)
//
#include <hip/hip_runtime.h>

#define TIMESTEPS 32
#define UNROLL 4

// Output-centric: each thread writes sequential float4s within ONE (b,t) plane,
// re-loading the matching input float4 (32x redundant reads, but the 19MB input
// stays hot in L2/LLC). This mirrors the pure-sequential store stream of the
// fill kernel, which measures 6.65+ TB/s on this chip vs our 5.2 TB/s scatter.
__global__ __launch_bounds__(256) void LatencyCoding_kernel(
    const float* __restrict__ x, float* __restrict__ out, int spatial4) {

    int plane = blockIdx.y;              // b*TIMESTEPS + t
    int t = plane & (TIMESTEPS - 1);
    int b = plane >> 5;                  // TIMESTEPS == 32

    int s4_base = blockIdx.x * (256 * UNROLL) + threadIdx.x;

    const float4* in4  = reinterpret_cast<const float4*>(x)   + (size_t)b     * spatial4;
    float4*       out4 = reinterpret_cast<float4*>(out)       + (size_t)plane * spatial4;

#pragma unroll
    for (int i = 0; i < UNROLL; ++i) {
        int s4 = s4_base + i * 256;
        if (s4 < spatial4) {
            float4 v = in4[s4];
            float c[4] = {v.x, v.y, v.z, v.w};
            float r[4];
#pragma unroll
            for (int j = 0; j < 4; ++j) {
                float xn = fminf(fmaxf(c[j], 0.0f), 1.0f);   // clip(x,0,1)
                int l = (int)((1.0f - xn) * 31.0f);          // trunc, same fp32 ops as ref
                l = min(max(l, 0), TIMESTEPS - 1);
                r[j] = (l == t && xn > 0.0f) ? 1.0f : 0.0f;
            }
            float4 o;
            o.x = r[0]; o.y = r[1]; o.z = r[2]; o.w = r[3];
            out4[s4] = o;
        }
    }
}

extern "C" void kernel_launch(void* const* d_in, const int* in_sizes, int n_in,
                              void* d_out, int out_size, void* d_ws, size_t ws_size,
                              hipStream_t stream) {
    const float* x   = (const float*)d_in[0];
    float*       out = (float*)d_out;

    int n = in_sizes[0];            // 32*3*224*224 = 4,816,896
    int B = 32;
    int spatial  = n / B;           // 150,528
    int spatial4 = spatial / 4;     // 37,632

    dim3 block(256, 1, 1);
    int gx = (spatial4 + 256 * UNROLL - 1) / (256 * UNROLL);  // 37
    dim3 grid(gx, B * TIMESTEPS, 1);                          // 37 x 1024

    LatencyCoding_kernel<<<grid, block, 0, stream>>>(x, out, spatial4);
}

// Round 3
// 123.925 us; speedup vs baseline: 1.3907x; 1.3907x over previous
//
#include <hip/hip_runtime.h>

#define TIMESTEPS 32
#define U 8   // float4s per thread (32 elements), i-stride 256 within the block

// Thread-centric read (input read exactly once), plane-major stores:
// each block owns a 2048-float4 (32KB) chunk of one image. Spike trains are
// precomputed as 32-bit one-hot masks in registers. The t-loop is OUTER so the
// block emits 32KB of contiguous stores per plane (8 back-to-back 1KB wave
// bursts) before jumping to the next plane -- vs R0's 1KB-per-plane scatter
// that sustained only 5.2 TB/s against the fill kernel's 6.6+.
__global__ __launch_bounds__(256) void LatencyCoding_kernel(
    const float* __restrict__ x, float* __restrict__ out, int spatial4) {

    int b = blockIdx.y;
    int base4 = blockIdx.x * (256 * U) + threadIdx.x;   // + i*256 per sub-chunk

    const float4* in4 = reinterpret_cast<const float4*>(x) + (size_t)b * spatial4;

    // One-hot time masks, one per element (4 per float4). Statically indexed.
    unsigned m[U][4];
#pragma unroll
    for (int i = 0; i < U; ++i) {
        int s4 = base4 + i * 256;
        float4 v = (s4 < spatial4) ? in4[s4] : make_float4(0.f, 0.f, 0.f, 0.f);
        float c[4] = {v.x, v.y, v.z, v.w};
#pragma unroll
        for (int j = 0; j < 4; ++j) {
            float xn = fminf(fmaxf(c[j], 0.0f), 1.0f);   // clip(x,0,1)
            int l = (int)((1.0f - xn) * 31.0f);          // trunc, same fp32 ops as ref
            l = min(max(l, 0), TIMESTEPS - 1);
            m[i][j] = (xn > 0.0f) ? (1u << l) : 0u;
        }
    }

    float4* outb = reinterpret_cast<float4*>(out) + (size_t)b * TIMESTEPS * spatial4;

    for (int t = 0; t < TIMESTEPS; ++t) {                // dynamic loop (i-cache friendly)
        float4* outp = outb + (size_t)t * spatial4;
#pragma unroll
        for (int i = 0; i < U; ++i) {
            int s4 = base4 + i * 256;
            if (s4 < spatial4) {                          // wave-uniform (spatial4 % 256 == 0)
                float4 o;
                o.x = ((m[i][0] >> t) & 1u) ? 1.0f : 0.0f;
                o.y = ((m[i][1] >> t) & 1u) ? 1.0f : 0.0f;
                o.z = ((m[i][2] >> t) & 1u) ? 1.0f : 0.0f;
                o.w = ((m[i][3] >> t) & 1u) ? 1.0f : 0.0f;
                outp[s4] = o;
            }
        }
    }
}

extern "C" void kernel_launch(void* const* d_in, const int* in_sizes, int n_in,
                              void* d_out, int out_size, void* d_ws, size_t ws_size,
                              hipStream_t stream) {
    const float* x   = (const float*)d_in[0];
    float*       out = (float*)d_out;

    int n = in_sizes[0];            // 32*3*224*224 = 4,816,896
    int B = 32;
    int spatial  = n / B;           // 150,528
    int spatial4 = spatial / 4;     // 37,632 (= 147 * 256)

    dim3 block(256, 1, 1);
    int gx = (spatial4 + 256 * U - 1) / (256 * U);      // 19
    dim3 grid(gx, B, 1);                                // 19 x 32 = 608 blocks

    LatencyCoding_kernel<<<grid, block, 0, stream>>>(x, out, spatial4);
}

// Round 5
// 110.238 us; speedup vs baseline: 1.5634x; 1.1242x over previous
//
#include <hip/hip_runtime.h>

#define TIMESTEPS 32

typedef float vfloat4 __attribute__((ext_vector_type(4)));  // clang-native vector:
// __builtin_nontemporal_store requires a real vector type, not HIP's float4 struct.

// R0 structure (input read exactly once, one float4/thread, 32 plane-strided
// coalesced stores) + NONTEMPORAL stores. R0 (scatter) and R2 (32KB bursts)
// both hit the same 5.2 TB/s wall -> pattern-independent limit, hypothesized
// to be L2 write-allocate/evict. nt stores bypass L2 like the 6.6+ TB/s fill.
__global__ __launch_bounds__(256) void LatencyCoding_kernel(
    const float* __restrict__ x, float* __restrict__ out,
    int n4, int spatial4 /* float4s per image */) {

    int idx4 = blockIdx.x * blockDim.x + threadIdx.x;
    if (idx4 >= n4) return;

    vfloat4 v = reinterpret_cast<const vfloat4*>(x)[idx4];

    int b  = idx4 / spatial4;            // batch index
    int s4 = idx4 - b * spatial4;        // float4 offset within the image

    unsigned m[4];
#pragma unroll
    for (int j = 0; j < 4; ++j) {
        float xn = fminf(fmaxf(v[j], 0.0f), 1.0f);   // clip(x,0,1)
        int l = (int)((1.0f - xn) * 31.0f);          // trunc, same fp32 ops as ref
        l = min(max(l, 0), TIMESTEPS - 1);
        m[j] = (xn > 0.0f) ? (1u << l) : 0u;         // one-hot time mask
    }

    vfloat4* out4 = reinterpret_cast<vfloat4*>(out) + (size_t)b * TIMESTEPS * spatial4 + s4;

#pragma unroll
    for (int t = 0; t < TIMESTEPS; ++t) {
        vfloat4 o;
        o.x = ((m[0] >> t) & 1u) ? 1.0f : 0.0f;
        o.y = ((m[1] >> t) & 1u) ? 1.0f : 0.0f;
        o.z = ((m[2] >> t) & 1u) ? 1.0f : 0.0f;
        o.w = ((m[3] >> t) & 1u) ? 1.0f : 0.0f;
        __builtin_nontemporal_store(o, out4 + (size_t)t * spatial4);
    }
}

extern "C" void kernel_launch(void* const* d_in, const int* in_sizes, int n_in,
                              void* d_out, int out_size, void* d_ws, size_t ws_size,
                              hipStream_t stream) {
    const float* x   = (const float*)d_in[0];
    float*       out = (float*)d_out;

    int n = in_sizes[0];            // 32*3*224*224 = 4,816,896
    int B = 32;
    int spatial4 = (n / B) / 4;     // 37,632
    int n4 = n / 4;                 // 1,204,224

    const int block = 256;
    int grid = (n4 + block - 1) / block;   // 4704
    LatencyCoding_kernel<<<grid, block, 0, stream>>>(x, out, n4, spatial4);
}